// Round 9
// baseline (290.414 us; speedup 1.0000x reference)
//
#include <hip/hip_runtime.h>
#include <hip/hip_bf16.h>
#include <stdint.h>
#include <math.h>

// ---------------------------------------------------------------------------
// MetaMultiHeadSelfAttention: B=4, S=2048, D=1024, H=16, hd=64, causal.
// R9: attn6 = interleaved causal pairing (block j owns q-tiles j & 31-j,
// stages each K-tile ONCE for both halves: 392 vs 528 stagings/(b,h)) +
// double-buffered K/V staging (one barrier per kt, staging overlaps compute;
// 41 KB LDS -> 3 blocks/CU). V^T production fused into QKV GEMM epilogue
// (vtrans kernel deleted). exp2 w/ scale folded into Wq; mask only on
// diagonal tiles. m97-style GEMMs.
// ---------------------------------------------------------------------------

typedef __bf16 bf16x8 __attribute__((ext_vector_type(8)));
typedef __bf16 bf16x4 __attribute__((ext_vector_type(4)));
typedef float  f32x4  __attribute__((ext_vector_type(4)));

static __device__ __forceinline__ f32x4 mfma16(bf16x8 a, bf16x8 b, f32x4 c) {
  return __builtin_amdgcn_mfma_f32_16x16x32_bf16(a, b, c, 0, 0, 0);
}

// async 16B/lane global->LDS; LDS dest = wave-uniform base + lane*16
static __device__ __forceinline__ void load16_lds(const void* g, void* l) {
  __builtin_amdgcn_global_load_lds(
      (const __attribute__((address_space(1))) unsigned int*)g,
      (__attribute__((address_space(3))) unsigned int*)l, 16, 0, 0);
}

// ---------------------------------------------------------------------------
// fp32 -> bf16, 8 elems/thread
// ---------------------------------------------------------------------------
__global__ __launch_bounds__(256) void cvt_f32_bf16(
    const float* __restrict__ in, __bf16* __restrict__ out, int n8) {
  int i = blockIdx.x * blockDim.x + threadIdx.x;
  if (i >= n8) return;
  const float4* in4 = (const float4*)in;
  float4 a = in4[2 * i], b = in4[2 * i + 1];
  __bf16 v[8];
  v[0] = (__bf16)a.x; v[1] = (__bf16)a.y; v[2] = (__bf16)a.z; v[3] = (__bf16)a.w;
  v[4] = (__bf16)b.x; v[5] = (__bf16)b.y; v[6] = (__bf16)b.z; v[7] = (__bf16)b.w;
  *(bf16x8*)(out + 8 * i) = *(bf16x8*)v;
}

// all 4 weight matrices: wq (pre-scaled by 0.125*log2 e), wk, wv -> wqkv; wo -> wob
__global__ __launch_bounds__(256) void cvt_w(
    const float* __restrict__ w0, const float* __restrict__ w1,
    const float* __restrict__ w2, const float* __restrict__ w3,
    __bf16* __restrict__ wqkv, __bf16* __restrict__ wo) {
  int blk = blockIdx.x;                 // 2048 blocks, 512 per matrix
  int m = blk >> 9;
  const float* src = (m == 0) ? w0 : (m == 1) ? w1 : (m == 2) ? w2 : w3;
  __bf16* dst = (m < 3) ? (wqkv + (size_t)m * (1024 * 1024)) : wo;
  const float s = (m == 0) ? 0.18033688f : 1.0f;   // 1/8 * log2(e)
  int i = (blk & 511) * 256 + threadIdx.x;
  const float4* in4 = (const float4*)src;
  float4 a = in4[2 * i], b = in4[2 * i + 1];
  __bf16 v[8];
  v[0] = (__bf16)(a.x * s); v[1] = (__bf16)(a.y * s);
  v[2] = (__bf16)(a.z * s); v[3] = (__bf16)(a.w * s);
  v[4] = (__bf16)(b.x * s); v[5] = (__bf16)(b.y * s);
  v[6] = (__bf16)(b.z * s); v[7] = (__bf16)(b.w * s);
  *(bf16x8*)(dst + 8 * i) = *(bf16x8*)v;
}

// ---------------------------------------------------------------------------
// Shared m97-style GEMM body: 128x128 tile, BK=32, global_load_lds width=16,
// unpadded LDS with XOR chunk swizzle. Epilogue differs per kernel below.
// ---------------------------------------------------------------------------
#define GEMM_BODY(Aptr, Bptr, Kdim)                                           \
  __shared__ __align__(16) __bf16 As[128 * 32];                               \
  __shared__ __align__(16) __bf16 Bs[128 * 32];                               \
  const int t = threadIdx.x;                                                  \
  const int lane = t & 63, w = t >> 6;                                        \
  const int wm = w >> 1, wn = w & 1;                                          \
  const int l15 = lane & 15, quad = lane >> 4;                                \
  const long rowA0 = (long)blockIdx.y * 128;                                  \
  const long rowB0 = (long)blockIdx.x * 128;                                  \
  const int r0 = w * 32 + (lane >> 2);                                        \
  const int r1 = r0 + 16;                                                     \
  const int c0 = (lane & 3) ^ ((r0 >> 1) & 3);                                \
  const int c1 = (lane & 3) ^ ((r1 >> 1) & 3);                                \
  const __bf16* pA0 = Aptr + (rowA0 + r0) * (long)Kdim + c0 * 8;              \
  const __bf16* pA1 = Aptr + (rowA0 + r1) * (long)Kdim + c1 * 8;              \
  const __bf16* pB0 = Bptr + (rowB0 + r0) * (long)Kdim + c0 * 8;              \
  const __bf16* pB1 = Bptr + (rowB0 + r1) * (long)Kdim + c1 * 8;              \
  __bf16* lA0 = As + (w * 32) * 32;                                           \
  __bf16* lA1 = As + (w * 32 + 16) * 32;                                      \
  __bf16* lB0 = Bs + (w * 32) * 32;                                           \
  __bf16* lB1 = Bs + (w * 32 + 16) * 32;                                      \
  int aoff[4], boff[4];                                                       \
  _Pragma("unroll")                                                           \
  for (int i = 0; i < 4; i++) {                                               \
    int Ra = wm * 64 + i * 16 + l15;                                          \
    aoff[i] = Ra * 32 + ((quad ^ ((Ra >> 1) & 3)) << 3);                      \
    int Rb = wn * 64 + i * 16 + l15;                                          \
    boff[i] = Rb * 32 + ((quad ^ ((Rb >> 1) & 3)) << 3);                      \
  }                                                                           \
  f32x4 acc[4][4] = {};                                                       \
  for (int k0 = 0; k0 < Kdim; k0 += 32) {                                     \
    load16_lds(pA0, lA0); load16_lds(pA1, lA1);                               \
    load16_lds(pB0, lB0); load16_lds(pB1, lB1);                               \
    pA0 += 32; pA1 += 32; pB0 += 32; pB1 += 32;                               \
    __syncthreads();                                                          \
    bf16x8 af[4], bfr[4];                                                     \
    _Pragma("unroll")                                                         \
    for (int i = 0; i < 4; i++) af[i] = *(const bf16x8*)(As + aoff[i]);       \
    _Pragma("unroll")                                                         \
    for (int i = 0; i < 4; i++) bfr[i] = *(const bf16x8*)(Bs + boff[i]);      \
    _Pragma("unroll")                                                         \
    for (int mt = 0; mt < 4; mt++)                                            \
      _Pragma("unroll")                                                       \
      for (int nt = 0; nt < 4; nt++)                                          \
        acc[mt][nt] = mfma16(af[mt], bfr[nt], acc[mt][nt]);                   \
    __syncthreads();                                                          \
  }

// out-projection GEMM: fp32 output, plain epilogue
__global__ __launch_bounds__(256) void gemm_out(
    const __bf16* __restrict__ A, const __bf16* __restrict__ Bw,
    float* __restrict__ C, int N, int K) {
  GEMM_BODY(A, Bw, K)
#pragma unroll
  for (int mt = 0; mt < 4; mt++)
#pragma unroll
    for (int nt = 0; nt < 4; nt++)
#pragma unroll
      for (int r = 0; r < 4; r++) {
        long row = rowA0 + wm * 64 + mt * 16 + quad * 4 + r;
        long col = rowB0 + wn * 64 + nt * 16 + l15;
        C[row * N + col] = acc[mt][nt][r];
      }
}

// QKV GEMM (N=3072): Q/K region -> QKV bf16 (normal); V region (col>=2048)
// writes straight into VT[(b*16+h)*64+d][s] as packed 4xbf16 (r-values are
// 4 consecutive s) — replaces the vtrans kernel.
__global__ __launch_bounds__(256) void gemm_qkvt(
    const __bf16* __restrict__ A, const __bf16* __restrict__ Bw,
    __bf16* __restrict__ QKV, __bf16* __restrict__ VTout, int K) {
  GEMM_BODY(A, Bw, K)
  if (rowB0 < 2048) {                    // Q/K region (block-uniform)
#pragma unroll
    for (int mt = 0; mt < 4; mt++)
#pragma unroll
      for (int nt = 0; nt < 4; nt++)
#pragma unroll
        for (int r = 0; r < 4; r++) {
          long row = rowA0 + wm * 64 + mt * 16 + quad * 4 + r;
          long col = rowB0 + wn * 64 + nt * 16 + l15;
          QKV[row * 3072 + col] = (__bf16)acc[mt][nt][r];
        }
  } else {                               // V region -> VT transposed
    const int b = (int)(rowA0 >> 11);
    const int sb = (int)(rowA0 & 2047);
#pragma unroll
    for (int mt = 0; mt < 4; mt++)
#pragma unroll
      for (int nt = 0; nt < 4; nt++) {
        int hcol = (int)(rowB0 - 2048) + wn * 64 + nt * 16 + l15;
        long vtrow = (long)(b * 16) * 64 + hcol;   // (b*16+h)*64 + d == b*1024 + hcol
        int s = sb + wm * 64 + mt * 16 + quad * 4;
        bf16x4 pk;
#pragma unroll
        for (int r = 0; r < 4; r++) pk[r] = (__bf16)acc[mt][nt][r];
        *(bf16x4*)(VTout + vtrow * 2048 + s) = pk;
      }
  }
}

// ---------------------------------------------------------------------------
// Causal attention R9 (attn6): 64-row q-tiles, interleaved pairing.
// Block j owns q-tiles A=j, B=31-j; stages K-tiles kt=0..31-j ONCE each
// (double-buffered), computes B always and A while kt<=j (kf regs reused).
// One barrier per kt; staging flies during compute. 4 waves x 16 q-rows.
// S^T = K Q^T (lane: key=quad*4+r, qrow=l15); exp2 (scale in Wq); packed
// 8B P writes to wave-private LDS; PV from LDS. Mask only diagonal tiles.
// ---------------------------------------------------------------------------
__global__ __launch_bounds__(256) void attn6(
    const __bf16* __restrict__ QKV, const __bf16* __restrict__ VT,
    __bf16* __restrict__ O) {
  constexpr int SD = 3072;
  constexpr int LDP = 72;
  __shared__ __align__(16) __bf16 Ks[2][64 * 64];
  __shared__ __align__(16) __bf16 Vs[2][64 * 64];
  __shared__ __align__(16) __bf16 Pw[4 * 16 * LDP];
  const int t = threadIdx.x;
  const int lane = t & 63, w = t >> 6;
  const int l15 = lane & 15, quad = lane >> 4;
  const int j = blockIdx.x, h = blockIdx.y, b = blockIdx.z;
  const long qbase = (long)b * 2048 * SD + h * 64;
  const long kbase = qbase + 1024;
  const long vtbase = (long)(b * 16 + h) * 64 * 2048;
  __bf16* Pme = Pw + w * 16 * LDP;

  // staging: wave w covers rows [w*16,+16) as 2 insts of 8 rows;
  // lane -> row sr (+8), global chunk scg, lands at pos lane&7
  const int sr = w * 16 + (lane >> 3);
  const int scg = (lane & 7) ^ (sr & 7);
  const int lo0 = (w * 16) * 64, lo1 = (w * 16 + 8) * 64;

  // swizzled fragment-read offsets: row R=nt*16+l15, chunk kk*4+quad at
  // pos (kk*4+quad)^(R&7); R&7 == l15&7
  int kvoff[4][2];
#pragma unroll
  for (int nt = 0; nt < 4; nt++)
#pragma unroll
    for (int kk = 0; kk < 2; kk++)
      kvoff[nt][kk] = (nt * 16 + l15) * 64 + (((kk * 4 + quad) ^ (l15 & 7)) << 3);

  const int qtA = j, qtB = 31 - j;
  const int rowA0 = qtA * 64 + w * 16;
  const int rowB0 = qtB * 64 + w * 16;
  const int qrowA = rowA0 + l15, qrowB = rowB0 + l15;

  // Q fragments for both halves (B-operand: n = qrow = l15)
  bf16x8 qfA[2], qfB[2];
#pragma unroll
  for (int kk = 0; kk < 2; kk++) {
    qfA[kk] = *(const bf16x8*)(QKV + qbase + (long)(rowA0 + l15) * SD + kk * 32 + quad * 8);
    qfB[kk] = *(const bf16x8*)(QKV + qbase + (long)(rowB0 + l15) * SD + kk * 32 + quad * 8);
  }

  f32x4 oA[4] = {}, oB[4] = {};
  float lA = 0.f, lB = 0.f;
  const int nkt = qtB + 1;               // kt = 0..31-j

  // prologue: stage kt=0 into buf 0
  load16_lds(QKV + kbase + (long)sr * SD + scg * 8, &Ks[0][lo0]);
  load16_lds(QKV + kbase + (long)(sr + 8) * SD + scg * 8, &Ks[0][lo1]);
  load16_lds(VT + vtbase + (long)sr * 2048 + scg * 8, &Vs[0][lo0]);
  load16_lds(VT + vtbase + (long)(sr + 8) * 2048 + scg * 8, &Vs[0][lo1]);

  for (int kt = 0; kt < nkt; kt++) {
    const int cur = kt & 1;
    __syncthreads();                     // drains staging(cur); frees buf cur^1
    if (kt + 1 < nkt) {                  // stage next tile into other buffer
      const long k0n = (long)(kt + 1) * 64;
      const int nb = cur ^ 1;
      load16_lds(QKV + kbase + (k0n + sr) * SD + scg * 8, &Ks[nb][lo0]);
      load16_lds(QKV + kbase + (k0n + sr + 8) * SD + scg * 8, &Ks[nb][lo1]);
      load16_lds(VT + vtbase + (long)sr * 2048 + k0n + scg * 8, &Vs[nb][lo0]);
      load16_lds(VT + vtbase + (long)(sr + 8) * 2048 + k0n + scg * 8, &Vs[nb][lo1]);
    }
    const __bf16* Kc = Ks[cur];
    const __bf16* Vc = Vs[cur];
    const int k0 = kt * 64;

    // K fragments (A-operand: m = key) — loaded once, reused by both halves
    bf16x8 kf[4][2];
#pragma unroll
    for (int nt = 0; nt < 4; nt++)
#pragma unroll
      for (int kk = 0; kk < 2; kk++)
        kf[nt][kk] = *(const bf16x8*)(Kc + kvoff[nt][kk]);

    // ---- half B (always active; diagonal at kt == qtB == nkt-1) ----
    {
      f32x4 st[4];
#pragma unroll
      for (int nt = 0; nt < 4; nt++) {
        f32x4 z = {0.f, 0.f, 0.f, 0.f};
        z = mfma16(kf[nt][0], qfB[0], z);
        st[nt] = mfma16(kf[nt][1], qfB[1], z);
      }
      if (kt == qtB) {
#pragma unroll
        for (int nt = 0; nt < 4; nt++) {
          const int keyb = k0 + nt * 16 + quad * 4;
          bf16x4 pb;
#pragma unroll
          for (int r = 0; r < 4; r++) {
            float e = exp2f(st[nt][r]);
            if (keyb + r > qrowB) e = 0.f;
            lB += e; pb[r] = (__bf16)e;
          }
          *(bf16x4*)(Pme + l15 * LDP + nt * 16 + quad * 4) = pb;
        }
      } else {
#pragma unroll
        for (int nt = 0; nt < 4; nt++) {
          bf16x4 pb;
#pragma unroll
          for (int r = 0; r < 4; r++) {
            float e = exp2f(st[nt][r]);
            lB += e; pb[r] = (__bf16)e;
          }
          *(bf16x4*)(Pme + l15 * LDP + nt * 16 + quad * 4) = pb;
        }
      }
#pragma unroll
      for (int kk = 0; kk < 2; kk++) {
        bf16x8 pf = *(const bf16x8*)(Pme + l15 * LDP + kk * 32 + quad * 8);
#pragma unroll
        for (int dt = 0; dt < 4; dt++) {
          bf16x8 vf = *(const bf16x8*)(Vc + kvoff[dt][kk]);
          oB[dt] = mfma16(pf, vf, oB[dt]);
        }
      }
    }

    // ---- half A (active while kt <= qtA; diagonal at kt == qtA) ----
    if (kt <= qtA) {
      f32x4 st[4];
#pragma unroll
      for (int nt = 0; nt < 4; nt++) {
        f32x4 z = {0.f, 0.f, 0.f, 0.f};
        z = mfma16(kf[nt][0], qfA[0], z);
        st[nt] = mfma16(kf[nt][1], qfA[1], z);
      }
      if (kt == qtA) {
#pragma unroll
        for (int nt = 0; nt < 4; nt++) {
          const int keyb = k0 + nt * 16 + quad * 4;
          bf16x4 pb;
#pragma unroll
          for (int r = 0; r < 4; r++) {
            float e = exp2f(st[nt][r]);
            if (keyb + r > qrowA) e = 0.f;
            lA += e; pb[r] = (__bf16)e;
          }
          *(bf16x4*)(Pme + l15 * LDP + nt * 16 + quad * 4) = pb;
        }
      } else {
#pragma unroll
        for (int nt = 0; nt < 4; nt++) {
          bf16x4 pb;
#pragma unroll
          for (int r = 0; r < 4; r++) {
            float e = exp2f(st[nt][r]);
            lA += e; pb[r] = (__bf16)e;
          }
          *(bf16x4*)(Pme + l15 * LDP + nt * 16 + quad * 4) = pb;
        }
      }
#pragma unroll
      for (int kk = 0; kk < 2; kk++) {
        bf16x8 pf = *(const bf16x8*)(Pme + l15 * LDP + kk * 32 + quad * 8);
#pragma unroll
        for (int dt = 0; dt < 4; dt++) {
          bf16x8 vf = *(const bf16x8*)(Vc + kvoff[dt][kk]);
          oA[dt] = mfma16(pf, vf, oA[dt]);
        }
      }
    }
  }

  // ---- epilogue: l = sum over quads; normalize; write O (both halves) ----
#pragma unroll
  for (int half = 0; half < 2; half++) {
    float l = half ? lB : lA;
    const int row0 = half ? rowB0 : rowA0;
    f32x4* oc = half ? oB : oA;
    l += __shfl_xor(l, 16, 64);
    l += __shfl_xor(l, 32, 64);          // lane holds l for qrow = l15
#pragma unroll
    for (int r = 0; r < 4; r++) {
      float lr = __shfl(l, quad * 4 + r, 64);
      float inv = 1.f / lr;
      int row = row0 + quad * 4 + r;
      long ob = ((long)b * 2048 + row) * 1024 + h * 64;
#pragma unroll
      for (int dt = 0; dt < 4; dt++)
        O[ob + dt * 16 + l15] = (__bf16)(oc[dt][r] * inv);
    }
  }
}

// ---------------------------------------------------------------------------
extern "C" void kernel_launch(void* const* d_in, const int* in_sizes, int n_in,
                              void* d_out, int out_size, void* d_ws, size_t ws_size,
                              hipStream_t stream) {
  const float* x  = (const float*)d_in[0];
  const float* wq = (const float*)d_in[1];
  const float* wk = (const float*)d_in[2];
  const float* wv = (const float*)d_in[3];
  const float* wo = (const float*)d_in[4];
  float* out = (float*)d_out;

  char* ws = (char*)d_ws;
  __bf16* xb   = (__bf16*)(ws);               // 16 MB [8192,1024]; reused as Ab
  __bf16* wqkv = (__bf16*)(ws + (16l << 20)); //  6 MB [3072,1024]
  __bf16* wob  = (__bf16*)(ws + (22l << 20)); //  2 MB
  __bf16* QKV  = (__bf16*)(ws + (24l << 20)); // 48 MB [8192,3072] (V third unused)
  __bf16* VT   = (__bf16*)(ws + (72l << 20)); // 16 MB [4096,2048] -> 88 MB total
  __bf16* Ab   = xb;                          // x dead after QKV gemm

  cvt_f32_bf16<<<4096, 256, 0, stream>>>(x, xb, 8192 * 1024 / 8);
  cvt_w<<<2048, 256, 0, stream>>>(wq, wk, wv, wo, wqkv, wob);

  // fused QKV projection; V region written transposed into VT (no vtrans)
  gemm_qkvt<<<dim3(24, 64), 256, 0, stream>>>(xb, wqkv, QKV, VT, 1024);

  // causal attention (interleaved-pair 64-row tiles, dbuf K/V) -> Ab
  attn6<<<dim3(16, 16, 4), 256, 0, stream>>>(QKV, VT, Ab);

  // output projection (fp32 out)
  gemm_out<<<dim3(8, 64), 256, 0, stream>>>(Ab, wob, out, 1024, 1024);
}